// Round 4
// baseline (778.058 us; speedup 1.0000x reference)
//
#include <hip/hip_runtime.h>
#include <cstdint>
#include <cstddef>

// Problem constants (fixed by reference)
#define NB      64      // batch
#define NBITS   4096
#define HD      64      // hidden
#define IN_DIM  4098
#define LMAXT   320
#define SEQ_STRIDE 336  // padded seq row (>= LMAX+2, mult of 16)
#define NTILE   257     // col tiles of 16 (4112 padded cols)
#define LOG2E   1.44269504088896340f

// Workspace layout (bytes), all 256-aligned
static constexpr size_t SEQ_OFF   = 0;                               // 86016
static constexpr size_t STEPS_OFF = 86016;                           // 256
static constexpr size_t LOSS_OFF  = 86272;                           // 256
static constexpr size_t XB_OFF    = 86528;                           // 64*320*64*2 = 2621440
static constexpr size_t WB_OFF    = XB_OFF + 2621440;                // 257*1024*2 = 526336
static constexpr size_t BO_OFF    = WB_OFF + 526336;                 // 4112*4

typedef __bf16    bf16x8 __attribute__((ext_vector_type(8)));
typedef float     f32x4  __attribute__((ext_vector_type(4)));
typedef _Float16  h2     __attribute__((ext_vector_type(2)));
typedef _Float16  h8     __attribute__((ext_vector_type(8)));

#if __has_builtin(__builtin_amdgcn_fdot2)
#define FDOT2(a, b, c) __builtin_amdgcn_fdot2((a), (b), (c), false)
#else
#define FDOT2(a, b, c) fmaf((float)(a)[0], (float)(b)[0], \
                        fmaf((float)(a)[1], (float)(b)[1], (c)))
#endif

// glibc's math.h macro-expands a declaration named __exp2f -> do NOT use that
// identifier; go straight to the HW builtin (v_exp_f32).
__device__ __forceinline__ float ex2(float x) {
#if __has_builtin(__builtin_amdgcn_exp2f)
  return __builtin_amdgcn_exp2f(x);
#else
  return __expf(x * 0.6931471805599453f);
#endif
}

__device__ __forceinline__ unsigned short f2bf(float f) {
  unsigned u = __float_as_uint(f);
  unsigned r = u + 0x7FFFu + ((u >> 16) & 1u);   // RNE
  return (unsigned short)(r >> 16);
}
__device__ __forceinline__ float bf2f(unsigned short u) {
  return __uint_as_float((unsigned)u << 16);
}
__device__ __forceinline__ bf16x8 ldb8(const unsigned short* p) {
  return *(const bf16x8*)p;
}
__device__ __forceinline__ void wave_lds_fence() {
  __asm__ __volatile__("s_waitcnt lgkmcnt(0)" ::: "memory");
}

// ---------------------------------------------------------------------------
// Kernel A: compaction. Stage 1 builds a 4096-bit LDS mask from a coalesced
// row read; stage 2 scans in perm order against LDS (no HBM gather).
// ---------------------------------------------------------------------------
__global__ __launch_bounds__(64) void k_setup(
    const float* __restrict__ true_fp, const int* __restrict__ perm,
    int* __restrict__ seq, int* __restrict__ steps,
    float* __restrict__ loss_accum) {
  const int b = blockIdx.x;
  const int j = threadIdx.x;
  if (b == 0 && j == 0) *loss_accum = 0.f;
  __shared__ unsigned long long bits[64];
  const float* row = true_fp + (size_t)b * NBITS;

  // lane j builds bits for original columns [j*64, j*64+64)
  {
    const float4* rv = (const float4*)(row + j * 64);
    unsigned long long w = 0ull;
#pragma unroll
    for (int i = 0; i < 16; ++i) {
      const float4 v = rv[i];
      w |= (unsigned long long)(v.x > 0.f) << (4 * i + 0);
      w |= (unsigned long long)(v.y > 0.f) << (4 * i + 1);
      w |= (unsigned long long)(v.z > 0.f) << (4 * i + 2);
      w |= (unsigned long long)(v.w > 0.f) << (4 * i + 3);
    }
    bits[j] = w;
  }
  wave_lds_fence();

  int* srow = seq + b * SEQ_STRIDE;
  int base = 0;
  for (int c0 = 0; c0 < IN_DIM; c0 += 64) {
    const int col = c0 + j;
    bool pred = false;
    if (col < IN_DIM) {
      if (col == 0 || col == IN_DIM - 1) pred = true;
      else {
        const int p = perm[col - 1];
        pred = (bits[p >> 6] >> (p & 63)) & 1ull;
      }
    }
    const unsigned long long mask = __ballot(pred);
    const int prefix = __popcll(mask & ((1ull << j) - 1ull));
    const int idx = base + prefix;
    if (pred && idx <= LMAXT) srow[idx] = col;
    base += __popcll(mask);
  }
  const int cap = (base <= LMAXT + 1) ? base : (LMAXT + 1);
  for (int i = cap + j; i < SEQ_STRIDE; i += 64) srow[i] = 0;
  if (j == 0) {
    int s = base - 1;
    if (s > LMAXT) s = LMAXT;
    steps[b] = s;
  }
}

// ---------------------------------------------------------------------------
// Kernel A2: bf16 fragment-major W tiles + pre-scaled shifted bias
// bo2[col] = (b_out[col]-30)*log2(e); pad -1e30. Coalesced W_out reads.
// ---------------------------------------------------------------------------
__global__ __launch_bounds__(256) void k_prep(
    const float* __restrict__ W_out, const float* __restrict__ b_out,
    unsigned short* __restrict__ Wb, float* __restrict__ bo2) {
  const int c = blockIdx.x;            // 0..256
  const int t = threadIdx.x;
  const int m = t & 15;                // col within tile
  const int col = c * 16 + m;
  const bool cok = col < IN_DIM;
#pragma unroll
  for (int kp = 0; kp < 4; ++kp) {
    const int k = kp * 16 + (t >> 4);
    const float v = cok ? W_out[(size_t)k * IN_DIM + col] : 0.f;
    Wb[c * 1024 + m * 64 + k] = f2bf(v);
  }
  if (t < 16) {
    const int cc = c * 16 + t;
    bo2[c * 16 + t] = (cc < IN_DIM) ? (b_out[cc] - 30.f) * LOG2E : -1e30f;
  }
}

// ---------------------------------------------------------------------------
// Kernel B: GRU recurrence. ONE WAVE per batch row, zero barriers.
// Thread g owns hidden unit g: computes all 3 gate dots via v_dot2_f32_f16
// (W_hh columns packed half2 in VGPRs), h broadcast via 8 same-address
// ds_read_b128 of fp16 h. Depth-4 register ring prefetch of W_ih rows.
// Emits bf16 Xb rows; zero-fills the padded tail.
// ---------------------------------------------------------------------------
__global__ __launch_bounds__(64) void k_gru(
    const float* __restrict__ embeds,
    const float* __restrict__ W_ih, const float* __restrict__ b_ih,
    const float* __restrict__ W_hh, const float* __restrict__ b_hh,
    const int* __restrict__ seq, const int* __restrict__ steps,
    unsigned short* __restrict__ Xb) {
  const int b = blockIdx.x;
  const int g = threadIdx.x;   // 0..63

  __shared__ __align__(16) _Float16 hl[HD];
  __shared__ int seqL[LMAXT + 2];

  for (int i = g; i < LMAXT + 2; i += 64) seqL[i] = seq[b * SEQ_STRIDE + i];

  // W_hh columns for unit g, packed as half2 over k-pairs
  h2 wr[32], wz[32], wn[32];
#pragma unroll
  for (int kk = 0; kk < 32; ++kk) {
    const float* w0 = W_hh + (size_t)(2 * kk) * 192;
    const float* w1 = W_hh + (size_t)(2 * kk + 1) * 192;
    h2 a, bzz, c;
    a[0]   = (_Float16)w0[g];        a[1]   = (_Float16)w1[g];
    bzz[0] = (_Float16)w0[64 + g];   bzz[1] = (_Float16)w1[64 + g];
    c[0]   = (_Float16)w0[128 + g];  c[1]   = (_Float16)w1[128 + g];
    wr[kk] = a; wz[kk] = bzz; wn[kk] = c;
  }
  const float bhr = b_hh[g], bhz = b_hh[64 + g], bhn = b_hh[128 + g];
  const float bir = b_ih[g], biz = b_ih[64 + g], bin_ = b_ih[128 + g];
  const int nst = steps[b];

  float hself = embeds[b * HD + g];
  hl[g] = (_Float16)hself;

  unsigned short* xrow = Xb + (size_t)b * LMAXT * HD + g;

  // depth-4 ring prefetch of this thread's 3 W_ih elements
  float pr[4], pz[4], pn[4];
#pragma unroll
  for (int d = 0; d < 4; ++d) {
    const float* rw = W_ih + (size_t)seqL[d] * 192;
    pr[d] = rw[g]; pz[d] = rw[64 + g]; pn[d] = rw[128 + g];
  }

  auto step = [&](int t, float gir, float giz, float gin) {
    wave_lds_fence();                       // prev h write -> visible
    const h8* hp = (const h8*)hl;
    float sr0 = 0.f, sr1 = 0.f, sz0 = 0.f, sz1 = 0.f, sn0 = 0.f, sn1 = 0.f;
#pragma unroll
    for (int i = 0; i < 8; ++i) {
      const h8 v = hp[i];
      const h2 p0 = __builtin_shufflevector(v, v, 0, 1);
      const h2 p1 = __builtin_shufflevector(v, v, 2, 3);
      const h2 p2 = __builtin_shufflevector(v, v, 4, 5);
      const h2 p3 = __builtin_shufflevector(v, v, 6, 7);
      const int k0 = i * 4;
      sr0 = FDOT2(p0, wr[k0 + 0], sr0);  sr1 = FDOT2(p1, wr[k0 + 1], sr1);
      sr0 = FDOT2(p2, wr[k0 + 2], sr0);  sr1 = FDOT2(p3, wr[k0 + 3], sr1);
      sz0 = FDOT2(p0, wz[k0 + 0], sz0);  sz1 = FDOT2(p1, wz[k0 + 1], sz1);
      sz0 = FDOT2(p2, wz[k0 + 2], sz0);  sz1 = FDOT2(p3, wz[k0 + 3], sz1);
      sn0 = FDOT2(p0, wn[k0 + 0], sn0);  sn1 = FDOT2(p1, wn[k0 + 1], sn1);
      sn0 = FDOT2(p2, wn[k0 + 2], sn0);  sn1 = FDOT2(p3, wn[k0 + 3], sn1);
    }
    const float ar = (sr0 + sr1) + bhr + (gir + bir);
    const float az = (sz0 + sz1) + bhz + (giz + biz);
    const float ghn = (sn0 + sn1) + bhn;
    const float rr = 1.f / (1.f + ex2(ar * -LOG2E));
    const float zz = 1.f / (1.f + ex2(az * -LOG2E));
    const float nx = (gin + bin_) + rr * ghn;
    const float e2 = ex2(fabsf(nx) * (-2.f * LOG2E));
    float th = (1.f - e2) / (1.f + e2);
    th = (nx < 0.f) ? -th : th;
    const float hn = th + zz * (hself - th);
    hself = hn;
    hl[g] = (_Float16)hn;
    xrow[(size_t)t * HD] = f2bf(hn);
  };

  const int nst4 = nst & ~3;
  int t = 0;
  for (; t < nst4; t += 4) {
#pragma unroll
    for (int u = 0; u < 4; ++u) {
      step(t + u, pr[u], pz[u], pn[u]);
      const int nt = t + u + 4;
      const int rix = seqL[(nt <= LMAXT + 1) ? nt : (LMAXT + 1)];
      const float* rw = W_ih + (size_t)rix * 192;
      pr[u] = rw[g]; pz[u] = rw[64 + g]; pn[u] = rw[128 + g];
    }
  }
  for (; t < nst; ++t) {   // tail <=3 steps: direct (stall is fine)
    const float* rw = W_ih + (size_t)seqL[t] * 192;
    step(t, rw[g], rw[64 + g], rw[128 + g]);
  }
  // zero-fill padded rows (ws is re-poisoned before every call)
  for (int i = nst * HD + g; i < LMAXT * HD; i += 64)
    Xb[(size_t)b * (LMAXT * HD) + i] = 0;
}

// ---------------------------------------------------------------------------
// Kernel C: MFMA bf16 fused projection + logsumexp + NLL. One wave per
// (b, 32-row chunk); depth-2 prefetch of Wb tiles (covers ~200cyc L2 lat).
// Grid: 640 blocks x 64 threads.
// ---------------------------------------------------------------------------
__global__ __launch_bounds__(64) void k_proj(
    const unsigned short* __restrict__ Xb,
    const unsigned short* __restrict__ Wb,
    const float* __restrict__ bo2,
    const int* __restrict__ seq, const int* __restrict__ steps,
    const float* __restrict__ b_out,
    float* __restrict__ loss_accum) {
  const int l  = threadIdx.x;
  const int b  = blockIdx.x / 10;
  const int t0 = (blockIdx.x % 10) * 32;
  const int nst = steps[b];

  __shared__ float srow[32];

  float nll = 0.f;
  if (t0 < nst) {
    const int lm = l & 15;
    const int q  = l >> 4;

    const unsigned short* xp0 = Xb + ((size_t)b * LMAXT + t0 + lm) * HD + q * 8;
    const bf16x8 a00 = ldb8(xp0);
    const bf16x8 a01 = ldb8(xp0 + 32);
    const bf16x8 a10 = ldb8(xp0 + 16 * HD);
    const bf16x8 a11 = ldb8(xp0 + 16 * HD + 32);

    float s[8];
#pragma unroll
    for (int i = 0; i < 8; ++i) s[i] = 0.f;

    const unsigned short* wp = Wb + lm * 64 + q * 8;
    const float* bop = bo2 + lm;

    bf16x8 B0[2], B1[2]; float BO[2];
    B0[0] = ldb8(wp);        B1[0] = ldb8(wp + 32);        BO[0] = bop[0];
    B0[1] = ldb8(wp + 1024); B1[1] = ldb8(wp + 1024 + 32); BO[1] = bop[16];

#pragma unroll 2
    for (int ct = 0; ct < NTILE; ++ct) {
      const int sl = ct & 1;
      const bf16x8 b0 = B0[sl], b1 = B1[sl];
      const float  bo = BO[sl];
      if (ct + 2 < NTILE) {
        const unsigned short* wpn = wp + (size_t)(ct + 2) * 1024;
        B0[sl] = ldb8(wpn); B1[sl] = ldb8(wpn + 32); BO[sl] = bop[(ct + 2) * 16];
      }
      f32x4 acc0 = {0.f, 0.f, 0.f, 0.f};
      f32x4 acc1 = {0.f, 0.f, 0.f, 0.f};
      acc0 = __builtin_amdgcn_mfma_f32_16x16x32_bf16(a00, b0, acc0, 0, 0, 0);
      acc0 = __builtin_amdgcn_mfma_f32_16x16x32_bf16(a01, b1, acc0, 0, 0, 0);
      acc1 = __builtin_amdgcn_mfma_f32_16x16x32_bf16(a10, b0, acc1, 0, 0, 0);
      acc1 = __builtin_amdgcn_mfma_f32_16x16x32_bf16(a11, b1, acc1, 0, 0, 0);
#pragma unroll
      for (int i = 0; i < 4; ++i) {
        s[i]     += ex2(fmaf(acc0[i], LOG2E, bo));
        s[4 + i] += ex2(fmaf(acc1[i], LOG2E, bo));
      }
    }

#pragma unroll
    for (int m = 1; m < 16; m <<= 1) {
#pragma unroll
      for (int i = 0; i < 8; ++i) s[i] += __shfl_xor(s[i], m, 64);
    }
    if (lm == 0) {
#pragma unroll
      for (int i = 0; i < 4; ++i) {
        srow[q * 4 + i]      = s[i];
        srow[16 + q * 4 + i] = s[4 + i];
      }
    }
    wave_lds_fence();

    if (l < 32) {
      const int t = t0 + l;
      if (t < nst) {
        const float ssum = srow[l];
        const int col = seq[b * SEQ_STRIDE + t + 1];
        const unsigned short* xr = Xb + ((size_t)b * LMAXT + t) * HD;
        const unsigned short* wc = Wb + (size_t)(col >> 4) * 1024 + (col & 15) * 64;
        float tl = b_out[col];
#pragma unroll 16
        for (int k = 0; k < 64; ++k)
          tl = fmaf(bf2f(xr[k]), bf2f(wc[k]), tl);
        nll = (30.f + __logf(ssum)) - tl;
      }
    }
  }
#pragma unroll
  for (int off = 32; off; off >>= 1) nll += __shfl_down(nll, off, 64);
  if (l == 0) atomicAdd(loss_accum, nll);
}

// ---------------------------------------------------------------------------
// Kernel D: finalize (loss_sum / count).
// ---------------------------------------------------------------------------
__global__ void k_final(const float* __restrict__ loss_accum,
                        const int* __restrict__ steps,
                        float* __restrict__ out) {
  if (threadIdx.x == 0 && blockIdx.x == 0) {
    int cnt = 0;
    for (int i = 0; i < NB; ++i) cnt += steps[i];
    out[0] = loss_accum[0] / (float)cnt;
  }
}

// ---------------------------------------------------------------------------
extern "C" void kernel_launch(void* const* d_in, const int* in_sizes, int n_in,
                              void* d_out, int out_size, void* d_ws,
                              size_t ws_size, hipStream_t stream) {
  const float* embeds  = (const float*)d_in[0];
  const float* true_fp = (const float*)d_in[1];
  const int*   perm    = (const int*)d_in[5];
  const float* W_ih    = (const float*)d_in[6];
  const float* b_ih    = (const float*)d_in[7];
  const float* W_hh    = (const float*)d_in[8];
  const float* b_hh    = (const float*)d_in[9];
  const float* W_out   = (const float*)d_in[10];
  const float* b_out   = (const float*)d_in[11];

  char*  ws     = (char*)d_ws;
  int*   seq    = (int*)(ws + SEQ_OFF);
  int*   steps  = (int*)(ws + STEPS_OFF);
  float* loss   = (float*)(ws + LOSS_OFF);
  unsigned short* Xb = (unsigned short*)(ws + XB_OFF);
  unsigned short* Wb = (unsigned short*)(ws + WB_OFF);
  float* bo2    = (float*)(ws + BO_OFF);
  float* out    = (float*)d_out;

  k_setup<<<NB, 64, 0, stream>>>(true_fp, perm, seq, steps, loss);
  k_prep<<<NTILE, 256, 0, stream>>>(W_out, b_out, Wb, bo2);
  k_gru<<<NB, 64, 0, stream>>>(embeds, W_ih, b_ih, W_hh, b_hh, seq, steps, Xb);
  k_proj<<<640, 64, 0, stream>>>(Xb, Wb, bo2, seq, steps, b_out, loss);
  k_final<<<1, 64, 0, stream>>>(loss, steps, out);
}

// Round 5
// 282.977 us; speedup vs baseline: 2.7495x; 2.7495x over previous
//
#include <hip/hip_runtime.h>
#include <cstdint>
#include <cstddef>

// Problem constants (fixed by reference)
#define NB      64      // batch
#define NBITS   4096
#define HD      64      // hidden
#define IN_DIM  4098
#define LMAXT   320
#define SEQ_STRIDE 336  // padded seq row (>= LMAX+2, mult of 16)
#define NTILE   257     // col tiles of 16 (4112 padded cols)
#define LOG2E   1.44269504088896340f
#define CSPLIT  8       // column-split waves per k_proj block

// Workspace layout (bytes), all 256-aligned
static constexpr size_t SEQ_OFF   = 0;                               // 86016
static constexpr size_t STEPS_OFF = 86016;                           // 256
static constexpr size_t LOSS_OFF  = 86272;                           // 256
static constexpr size_t XB_OFF    = 86528;                           // 64*320*64*2 = 2621440
static constexpr size_t WB_OFF    = XB_OFF + 2621440;                // 257*1024*2 = 526336
static constexpr size_t BO_OFF    = WB_OFF + 526336;                 // 4112*4

typedef __bf16    bf16x8 __attribute__((ext_vector_type(8)));
typedef float     f32x4  __attribute__((ext_vector_type(4)));
typedef _Float16  h2     __attribute__((ext_vector_type(2)));
typedef _Float16  h8     __attribute__((ext_vector_type(8)));

#if __has_builtin(__builtin_amdgcn_fdot2)
#define FDOT2(a, b, c) __builtin_amdgcn_fdot2((a), (b), (c), false)
#else
#define FDOT2(a, b, c) fmaf((float)(a)[0], (float)(b)[0], \
                        fmaf((float)(a)[1], (float)(b)[1], (c)))
#endif

// glibc's math.h macro-expands a declaration named __exp2f -> do NOT use that
// identifier; go straight to the HW builtin (v_exp_f32).
__device__ __forceinline__ float ex2(float x) {
#if __has_builtin(__builtin_amdgcn_exp2f)
  return __builtin_amdgcn_exp2f(x);
#else
  return __expf(x * 0.6931471805599453f);
#endif
}

__device__ __forceinline__ unsigned short f2bf(float f) {
  unsigned u = __float_as_uint(f);
  unsigned r = u + 0x7FFFu + ((u >> 16) & 1u);   // RNE
  return (unsigned short)(r >> 16);
}
__device__ __forceinline__ float bf2f(unsigned short u) {
  return __uint_as_float((unsigned)u << 16);
}
__device__ __forceinline__ bf16x8 ldb8(const unsigned short* p) {
  return *(const bf16x8*)p;
}
__device__ __forceinline__ void wave_lds_fence() {
  __asm__ __volatile__("s_waitcnt lgkmcnt(0)" ::: "memory");
}

// ---------------------------------------------------------------------------
// Kernel A: compaction. Stage 1 builds a 4096-bit LDS mask from a coalesced
// row read; stage 2 scans in perm order against LDS (no HBM gather).
// ---------------------------------------------------------------------------
__global__ __launch_bounds__(64) void k_setup(
    const float* __restrict__ true_fp, const int* __restrict__ perm,
    int* __restrict__ seq, int* __restrict__ steps,
    float* __restrict__ loss_accum) {
  const int b = blockIdx.x;
  const int j = threadIdx.x;
  if (b == 0 && j == 0) *loss_accum = 0.f;
  __shared__ unsigned long long bits[64];
  const float* row = true_fp + (size_t)b * NBITS;

  // lane j builds bits for original columns [j*64, j*64+64)
  {
    const float4* rv = (const float4*)(row + j * 64);
    unsigned long long w = 0ull;
#pragma unroll
    for (int i = 0; i < 16; ++i) {
      const float4 v = rv[i];
      w |= (unsigned long long)(v.x > 0.f) << (4 * i + 0);
      w |= (unsigned long long)(v.y > 0.f) << (4 * i + 1);
      w |= (unsigned long long)(v.z > 0.f) << (4 * i + 2);
      w |= (unsigned long long)(v.w > 0.f) << (4 * i + 3);
    }
    bits[j] = w;
  }
  wave_lds_fence();

  int* srow = seq + b * SEQ_STRIDE;
  int base = 0;
  for (int c0 = 0; c0 < IN_DIM; c0 += 64) {
    const int col = c0 + j;
    bool pred = false;
    if (col < IN_DIM) {
      if (col == 0 || col == IN_DIM - 1) pred = true;
      else {
        const int p = perm[col - 1];
        pred = (bits[p >> 6] >> (p & 63)) & 1ull;
      }
    }
    const unsigned long long mask = __ballot(pred);
    const int prefix = __popcll(mask & ((1ull << j) - 1ull));
    const int idx = base + prefix;
    if (pred && idx <= LMAXT) srow[idx] = col;
    base += __popcll(mask);
  }
  const int cap = (base <= LMAXT + 1) ? base : (LMAXT + 1);
  for (int i = cap + j; i < SEQ_STRIDE; i += 64) srow[i] = 0;
  if (j == 0) {
    int s = base - 1;
    if (s > LMAXT) s = LMAXT;
    steps[b] = s;
  }
}

// ---------------------------------------------------------------------------
// Kernel A2: bf16 fragment-major W tiles + pre-scaled shifted bias
// bo2[col] = (b_out[col]-30)*log2(e); pad -1e30. Coalesced W_out reads.
// ---------------------------------------------------------------------------
__global__ __launch_bounds__(256) void k_prep(
    const float* __restrict__ W_out, const float* __restrict__ b_out,
    unsigned short* __restrict__ Wb, float* __restrict__ bo2) {
  const int c = blockIdx.x;            // 0..256
  const int t = threadIdx.x;
  const int m = t & 15;                // col within tile
  const int col = c * 16 + m;
  const bool cok = col < IN_DIM;
#pragma unroll
  for (int kp = 0; kp < 4; ++kp) {
    const int k = kp * 16 + (t >> 4);
    const float v = cok ? W_out[(size_t)k * IN_DIM + col] : 0.f;
    Wb[c * 1024 + m * 64 + k] = f2bf(v);
  }
  if (t < 16) {
    const int cc = c * 16 + t;
    bo2[c * 16 + t] = (cc < IN_DIM) ? (b_out[cc] - 30.f) * LOG2E : -1e30f;
  }
}

// ---------------------------------------------------------------------------
// Kernel B: GRU recurrence. ONE WAVE per batch row, zero barriers.
// Thread g owns hidden unit g: computes all 3 gate dots via v_dot2_f32_f16
// (W_hh columns packed half2 in VGPRs), h broadcast via 8 same-address
// ds_read_b128 of fp16 h. Depth-4 register ring prefetch of W_ih rows.
// Emits bf16 Xb rows; zero-fills the padded tail.
// ---------------------------------------------------------------------------
__global__ __launch_bounds__(64) void k_gru(
    const float* __restrict__ embeds,
    const float* __restrict__ W_ih, const float* __restrict__ b_ih,
    const float* __restrict__ W_hh, const float* __restrict__ b_hh,
    const int* __restrict__ seq, const int* __restrict__ steps,
    unsigned short* __restrict__ Xb) {
  const int b = blockIdx.x;
  const int g = threadIdx.x;   // 0..63

  __shared__ __align__(16) _Float16 hl[HD];
  __shared__ int seqL[LMAXT + 2];

  for (int i = g; i < LMAXT + 2; i += 64) seqL[i] = seq[b * SEQ_STRIDE + i];

  // W_hh columns for unit g, packed as half2 over k-pairs
  h2 wr[32], wz[32], wn[32];
#pragma unroll
  for (int kk = 0; kk < 32; ++kk) {
    const float* w0 = W_hh + (size_t)(2 * kk) * 192;
    const float* w1 = W_hh + (size_t)(2 * kk + 1) * 192;
    h2 a, bzz, c;
    a[0]   = (_Float16)w0[g];        a[1]   = (_Float16)w1[g];
    bzz[0] = (_Float16)w0[64 + g];   bzz[1] = (_Float16)w1[64 + g];
    c[0]   = (_Float16)w0[128 + g];  c[1]   = (_Float16)w1[128 + g];
    wr[kk] = a; wz[kk] = bzz; wn[kk] = c;
  }
  const float bhr = b_hh[g], bhz = b_hh[64 + g], bhn = b_hh[128 + g];
  const float bir = b_ih[g], biz = b_ih[64 + g], bin_ = b_ih[128 + g];
  const int nst = steps[b];

  float hself = embeds[b * HD + g];
  hl[g] = (_Float16)hself;

  unsigned short* xrow = Xb + (size_t)b * LMAXT * HD + g;

  // depth-4 ring prefetch of this thread's 3 W_ih elements
  float pr[4], pz[4], pn[4];
#pragma unroll
  for (int d = 0; d < 4; ++d) {
    const float* rw = W_ih + (size_t)seqL[d] * 192;
    pr[d] = rw[g]; pz[d] = rw[64 + g]; pn[d] = rw[128 + g];
  }

  auto step = [&](int t, float gir, float giz, float gin) {
    wave_lds_fence();                       // prev h write -> visible
    const h8* hp = (const h8*)hl;
    float sr0 = 0.f, sr1 = 0.f, sz0 = 0.f, sz1 = 0.f, sn0 = 0.f, sn1 = 0.f;
#pragma unroll
    for (int i = 0; i < 8; ++i) {
      const h8 v = hp[i];
      const h2 p0 = __builtin_shufflevector(v, v, 0, 1);
      const h2 p1 = __builtin_shufflevector(v, v, 2, 3);
      const h2 p2 = __builtin_shufflevector(v, v, 4, 5);
      const h2 p3 = __builtin_shufflevector(v, v, 6, 7);
      const int k0 = i * 4;
      sr0 = FDOT2(p0, wr[k0 + 0], sr0);  sr1 = FDOT2(p1, wr[k0 + 1], sr1);
      sr0 = FDOT2(p2, wr[k0 + 2], sr0);  sr1 = FDOT2(p3, wr[k0 + 3], sr1);
      sz0 = FDOT2(p0, wz[k0 + 0], sz0);  sz1 = FDOT2(p1, wz[k0 + 1], sz1);
      sz0 = FDOT2(p2, wz[k0 + 2], sz0);  sz1 = FDOT2(p3, wz[k0 + 3], sz1);
      sn0 = FDOT2(p0, wn[k0 + 0], sn0);  sn1 = FDOT2(p1, wn[k0 + 1], sn1);
      sn0 = FDOT2(p2, wn[k0 + 2], sn0);  sn1 = FDOT2(p3, wn[k0 + 3], sn1);
    }
    const float ar = (sr0 + sr1) + bhr + (gir + bir);
    const float az = (sz0 + sz1) + bhz + (giz + biz);
    const float ghn = (sn0 + sn1) + bhn;
    const float rr = 1.f / (1.f + ex2(ar * -LOG2E));
    const float zz = 1.f / (1.f + ex2(az * -LOG2E));
    const float nx = (gin + bin_) + rr * ghn;
    const float e2 = ex2(fabsf(nx) * (-2.f * LOG2E));
    float th = (1.f - e2) / (1.f + e2);
    th = (nx < 0.f) ? -th : th;
    const float hn = th + zz * (hself - th);
    hself = hn;
    hl[g] = (_Float16)hn;
    xrow[(size_t)t * HD] = f2bf(hn);
  };

  const int nst4 = nst & ~3;
  int t = 0;
  for (; t < nst4; t += 4) {
#pragma unroll
    for (int u = 0; u < 4; ++u) {
      step(t + u, pr[u], pz[u], pn[u]);
      const int nt = t + u + 4;
      const int rix = seqL[(nt <= LMAXT + 1) ? nt : (LMAXT + 1)];
      const float* rw = W_ih + (size_t)rix * 192;
      pr[u] = rw[g]; pz[u] = rw[64 + g]; pn[u] = rw[128 + g];
    }
  }
  for (; t < nst; ++t) {   // tail <=3 steps: direct (stall is fine)
    const float* rw = W_ih + (size_t)seqL[t] * 192;
    step(t, rw[g], rw[64 + g], rw[128 + g]);
  }
  // zero-fill padded rows (ws is re-poisoned before every call)
  for (int i = nst * HD + g; i < LMAXT * HD; i += 64)
    Xb[(size_t)b * (LMAXT * HD) + i] = 0;
}

// ---------------------------------------------------------------------------
// Kernel C: MFMA bf16 fused projection + logsumexp + NLL.
// Block = 512 threads = 8 waves sharing one (b, 32-row chunk); waves split
// the 257 column tiles (33 each -> 66 KB Wb stream per wave). Partial exp
// sums merge via LDS. Grid 640 blocks -> 20 waves/CU (TLP hides L2 latency;
// R4's 64-thr version had 2.5 waves/CU and was latency-starved at 560 us).
// ---------------------------------------------------------------------------
__global__ __launch_bounds__(512) void k_proj(
    const unsigned short* __restrict__ Xb,
    const unsigned short* __restrict__ Wb,
    const float* __restrict__ bo2,
    const int* __restrict__ seq, const int* __restrict__ steps,
    const float* __restrict__ b_out,
    float* __restrict__ loss_accum) {
  const int l  = threadIdx.x & 63;
  const int wv = threadIdx.x >> 6;         // 0..7 column-split wave id
  const int b  = blockIdx.x / 10;
  const int t0 = (blockIdx.x % 10) * 32;
  const int nst = steps[b];
  const bool active = (t0 < nst);          // block-uniform

  __shared__ float spart[CSPLIT][32];

  if (active) {
    const int lm = l & 15;
    const int q  = l >> 4;

    const unsigned short* xp0 = Xb + ((size_t)b * LMAXT + t0 + lm) * HD + q * 8;
    const bf16x8 a00 = ldb8(xp0);
    const bf16x8 a01 = ldb8(xp0 + 32);
    const bf16x8 a10 = ldb8(xp0 + 16 * HD);
    const bf16x8 a11 = ldb8(xp0 + 16 * HD + 32);

    float s[8];
#pragma unroll
    for (int i = 0; i < 8; ++i) s[i] = 0.f;

    const int ct0 = wv * 33;
    const int ct1 = (ct0 + 33 < NTILE) ? (ct0 + 33) : NTILE;   // wave 7: 26

    const unsigned short* wp = Wb + lm * 64 + q * 8;
    const float* bop = bo2 + lm;

    bf16x8 b0 = ldb8(wp + (size_t)ct0 * 1024);
    bf16x8 b1 = ldb8(wp + (size_t)ct0 * 1024 + 32);
    float  bo = bop[ct0 * 16];
    for (int ct = ct0; ct < ct1; ++ct) {
      bf16x8 nb0, nb1; float nbo;
      if (ct + 1 < ct1) {
        const unsigned short* wpn = wp + (size_t)(ct + 1) * 1024;
        nb0 = ldb8(wpn); nb1 = ldb8(wpn + 32); nbo = bop[(ct + 1) * 16];
      }
      f32x4 acc0 = {0.f, 0.f, 0.f, 0.f};
      f32x4 acc1 = {0.f, 0.f, 0.f, 0.f};
      acc0 = __builtin_amdgcn_mfma_f32_16x16x32_bf16(a00, b0, acc0, 0, 0, 0);
      acc0 = __builtin_amdgcn_mfma_f32_16x16x32_bf16(a01, b1, acc0, 0, 0, 0);
      acc1 = __builtin_amdgcn_mfma_f32_16x16x32_bf16(a10, b0, acc1, 0, 0, 0);
      acc1 = __builtin_amdgcn_mfma_f32_16x16x32_bf16(a11, b1, acc1, 0, 0, 0);
#pragma unroll
      for (int i = 0; i < 4; ++i) {
        s[i]     += ex2(fmaf(acc0[i], LOG2E, bo));
        s[4 + i] += ex2(fmaf(acc1[i], LOG2E, bo));
      }
      if (ct + 1 < ct1) { b0 = nb0; b1 = nb1; bo = nbo; }
    }

    // reduce across the 16 lanes (lm) sharing each row
#pragma unroll
    for (int m = 1; m < 16; m <<= 1) {
#pragma unroll
      for (int i = 0; i < 8; ++i) s[i] += __shfl_xor(s[i], m, 64);
    }
    // D-layout: lane q*16 holds rows q*4+i (tile0) / 16+q*4+i (tile1)
    if (lm == 0) {
#pragma unroll
      for (int i = 0; i < 4; ++i) {
        spart[wv][q * 4 + i]      = s[i];
        spart[wv][16 + q * 4 + i] = s[4 + i];
      }
    }
  }
  __syncthreads();

  float nll = 0.f;
  if (active && threadIdx.x < 32) {
    const int t = t0 + threadIdx.x;
    if (t < nst) {
      float ssum = 0.f;
#pragma unroll
      for (int c = 0; c < CSPLIT; ++c) ssum += spart[c][threadIdx.x];
      const int col = seq[b * SEQ_STRIDE + t + 1];
      // target logit from the SAME bf16 operands (consistent cancellation)
      const unsigned short* xr = Xb + ((size_t)b * LMAXT + t) * HD;
      const unsigned short* wc = Wb + (size_t)(col >> 4) * 1024 + (col & 15) * 64;
      float tl = b_out[col];
#pragma unroll 16
      for (int k = 0; k < 64; ++k)
        tl = fmaf(bf2f(xr[k]), bf2f(wc[k]), tl);
      nll = (30.f + __logf(ssum)) - tl;
    }
  }
  if (threadIdx.x < 64) {
#pragma unroll
    for (int off = 32; off; off >>= 1) nll += __shfl_down(nll, off, 64);
    if (threadIdx.x == 0) atomicAdd(loss_accum, nll);
  }
}

// ---------------------------------------------------------------------------
// Kernel D: finalize (loss_sum / count).
// ---------------------------------------------------------------------------
__global__ void k_final(const float* __restrict__ loss_accum,
                        const int* __restrict__ steps,
                        float* __restrict__ out) {
  if (threadIdx.x == 0 && blockIdx.x == 0) {
    int cnt = 0;
    for (int i = 0; i < NB; ++i) cnt += steps[i];
    out[0] = loss_accum[0] / (float)cnt;
  }
}

// ---------------------------------------------------------------------------
extern "C" void kernel_launch(void* const* d_in, const int* in_sizes, int n_in,
                              void* d_out, int out_size, void* d_ws,
                              size_t ws_size, hipStream_t stream) {
  const float* embeds  = (const float*)d_in[0];
  const float* true_fp = (const float*)d_in[1];
  const int*   perm    = (const int*)d_in[5];
  const float* W_ih    = (const float*)d_in[6];
  const float* b_ih    = (const float*)d_in[7];
  const float* W_hh    = (const float*)d_in[8];
  const float* b_hh    = (const float*)d_in[9];
  const float* W_out   = (const float*)d_in[10];
  const float* b_out   = (const float*)d_in[11];

  char*  ws     = (char*)d_ws;
  int*   seq    = (int*)(ws + SEQ_OFF);
  int*   steps  = (int*)(ws + STEPS_OFF);
  float* loss   = (float*)(ws + LOSS_OFF);
  unsigned short* Xb = (unsigned short*)(ws + XB_OFF);
  unsigned short* Wb = (unsigned short*)(ws + WB_OFF);
  float* bo2    = (float*)(ws + BO_OFF);
  float* out    = (float*)d_out;

  k_setup<<<NB, 64, 0, stream>>>(true_fp, perm, seq, steps, loss);
  k_prep<<<NTILE, 256, 0, stream>>>(W_out, b_out, Wb, bo2);
  k_gru<<<NB, 64, 0, stream>>>(embeds, W_ih, b_ih, W_hh, b_hh, seq, steps, Xb);
  k_proj<<<640, 512, 0, stream>>>(Xb, Wb, bo2, seq, steps, b_out, loss);
  k_final<<<1, 64, 0, stream>>>(loss, steps, out);
}

// Round 6
// 261.637 us; speedup vs baseline: 2.9738x; 1.0816x over previous
//
#include <hip/hip_runtime.h>
#include <hip/hip_fp16.h>
#include <cstdint>
#include <cstddef>

// Problem constants (fixed by reference)
#define NB      64      // batch
#define NBITS   4096
#define HD      64      // hidden
#define IN_DIM  4098
#define LMAXT   320
#define SEQ_STRIDE 336  // padded seq row (>= LMAX+2, mult of 16)
#define NTILE   257     // col tiles of 16 (4112 padded cols)
#define LOG2E   1.44269504088896340f
#define CSPLIT  8       // column-split waves per k_proj block

// Workspace layout (bytes), all 256-aligned
static constexpr size_t SEQ_OFF   = 0;                               // 86016
static constexpr size_t STEPS_OFF = 86016;                           // 256
static constexpr size_t LOSS_OFF  = 86272;                           // 256
static constexpr size_t XB_OFF    = 86528;                           // 64*320*64*2 = 2621440
static constexpr size_t WB_OFF    = XB_OFF + 2621440;                // 257*1024*2 = 526336
static constexpr size_t BO_OFF    = WB_OFF + 526336;                 // 4112*4

typedef __bf16    bf16x8 __attribute__((ext_vector_type(8)));
typedef float     f32x4  __attribute__((ext_vector_type(4)));
typedef _Float16  h8     __attribute__((ext_vector_type(8)));

// glibc's math.h macro-expands a declaration named __exp2f -> do NOT use that
// identifier; go straight to the HW builtin (v_exp_f32).
__device__ __forceinline__ float ex2(float x) {
#if __has_builtin(__builtin_amdgcn_exp2f)
  return __builtin_amdgcn_exp2f(x);
#else
  return __expf(x * 0.6931471805599453f);
#endif
}
// raw v_rcp_f32 (~1 ulp): keeps the gate chain off the slow exact-div sequence
__device__ __forceinline__ float frcp(float x) {
#if __has_builtin(__builtin_amdgcn_rcpf)
  return __builtin_amdgcn_rcpf(x);
#else
  return 1.f / x;
#endif
}

__device__ __forceinline__ unsigned short f2bf(float f) {
  unsigned u = __float_as_uint(f);
  unsigned r = u + 0x7FFFu + ((u >> 16) & 1u);   // RNE
  return (unsigned short)(r >> 16);
}
__device__ __forceinline__ float bf2f(unsigned short u) {
  return __uint_as_float((unsigned)u << 16);
}
__device__ __forceinline__ bf16x8 ldb8(const unsigned short* p) {
  return *(const bf16x8*)p;
}
__device__ __forceinline__ void wave_lds_fence() {
  __asm__ __volatile__("s_waitcnt lgkmcnt(0)" ::: "memory");
}

// ---------------------------------------------------------------------------
// Kernel A: compaction. Stage 1 builds a 4096-bit LDS mask from a coalesced
// row read; stage 2 scans in perm order against LDS (no HBM gather).
// ---------------------------------------------------------------------------
__global__ __launch_bounds__(64) void k_setup(
    const float* __restrict__ true_fp, const int* __restrict__ perm,
    int* __restrict__ seq, int* __restrict__ steps,
    float* __restrict__ loss_accum) {
  const int b = blockIdx.x;
  const int j = threadIdx.x;
  if (b == 0 && j == 0) *loss_accum = 0.f;
  __shared__ unsigned long long bits[64];
  const float* row = true_fp + (size_t)b * NBITS;

  {
    const float4* rv = (const float4*)(row + j * 64);
    unsigned long long w = 0ull;
#pragma unroll
    for (int i = 0; i < 16; ++i) {
      const float4 v = rv[i];
      w |= (unsigned long long)(v.x > 0.f) << (4 * i + 0);
      w |= (unsigned long long)(v.y > 0.f) << (4 * i + 1);
      w |= (unsigned long long)(v.z > 0.f) << (4 * i + 2);
      w |= (unsigned long long)(v.w > 0.f) << (4 * i + 3);
    }
    bits[j] = w;
  }
  wave_lds_fence();

  int* srow = seq + b * SEQ_STRIDE;
  int base = 0;
  for (int c0 = 0; c0 < IN_DIM; c0 += 64) {
    const int col = c0 + j;
    bool pred = false;
    if (col < IN_DIM) {
      if (col == 0 || col == IN_DIM - 1) pred = true;
      else {
        const int p = perm[col - 1];
        pred = (bits[p >> 6] >> (p & 63)) & 1ull;
      }
    }
    const unsigned long long mask = __ballot(pred);
    const int prefix = __popcll(mask & ((1ull << j) - 1ull));
    const int idx = base + prefix;
    if (pred && idx <= LMAXT) srow[idx] = col;
    base += __popcll(mask);
  }
  const int cap = (base <= LMAXT + 1) ? base : (LMAXT + 1);
  for (int i = cap + j; i < SEQ_STRIDE; i += 64) srow[i] = 0;
  if (j == 0) {
    int s = base - 1;
    if (s > LMAXT) s = LMAXT;
    steps[b] = s;
  }
}

// ---------------------------------------------------------------------------
// Kernel A2: bf16 fragment-major W tiles + pre-scaled shifted bias
// bo2[col] = (b_out[col]-30)*log2(e); pad -1e30. Coalesced W_out reads.
// ---------------------------------------------------------------------------
__global__ __launch_bounds__(256) void k_prep(
    const float* __restrict__ W_out, const float* __restrict__ b_out,
    unsigned short* __restrict__ Wb, float* __restrict__ bo2) {
  const int c = blockIdx.x;            // 0..256
  const int t = threadIdx.x;
  const int m = t & 15;                // col within tile
  const int col = c * 16 + m;
  const bool cok = col < IN_DIM;
#pragma unroll
  for (int kp = 0; kp < 4; ++kp) {
    const int k = kp * 16 + (t >> 4);
    const float v = cok ? W_out[(size_t)k * IN_DIM + col] : 0.f;
    Wb[c * 1024 + m * 64 + k] = f2bf(v);
  }
  if (t < 16) {
    const int cc = c * 16 + t;
    bo2[c * 16 + t] = (cc < IN_DIM) ? (b_out[cc] - 30.f) * LOG2E : -1e30f;
  }
}

// ---------------------------------------------------------------------------
// Kernel B: GRU recurrence. ONE WAVE per batch row, zero barriers.
// __launch_bounds__(64, 1): R5's VGPR_Count=84 proved the compiler capped
// registers for 6-wave occupancy and SPILLED the 96-reg W_hh array to
// scratch (reloaded every step -> 1215 cyc/step). Occupancy is irrelevant
// here (64 lone-wave blocks on 256 CUs) -- let it use ~200 VGPRs.
// Gate dots via v_pk_fma_f16 (__hfma2), gates via v_rcp_f32.
// ---------------------------------------------------------------------------
__global__ __launch_bounds__(64, 1) void k_gru(
    const float* __restrict__ embeds,
    const float* __restrict__ W_ih, const float* __restrict__ b_ih,
    const float* __restrict__ W_hh, const float* __restrict__ b_hh,
    const int* __restrict__ seq, const int* __restrict__ steps,
    unsigned short* __restrict__ Xb) {
  const int b = blockIdx.x;
  const int g = threadIdx.x;   // 0..63

  __shared__ __align__(16) _Float16 hl[HD];
  __shared__ int seqL[LMAXT + 2];

  for (int i = g; i < LMAXT + 2; i += 64) seqL[i] = seq[b * SEQ_STRIDE + i];

  // W_hh columns for unit g, packed as half2 over k-pairs (96 VGPRs)
  __half2 wr2[32], wz2[32], wn2[32];
#pragma unroll
  for (int kk = 0; kk < 32; ++kk) {
    const float* w0 = W_hh + (size_t)(2 * kk) * 192;
    const float* w1 = W_hh + (size_t)(2 * kk + 1) * 192;
    wr2[kk] = __floats2half2_rn(w0[g],       w1[g]);
    wz2[kk] = __floats2half2_rn(w0[64 + g],  w1[64 + g]);
    wn2[kk] = __floats2half2_rn(w0[128 + g], w1[128 + g]);
  }
  const float bhn = b_hh[128 + g];
  const float br  = b_ih[g] + b_hh[g];              // folded r-gate bias
  const float bz  = b_ih[64 + g] + b_hh[64 + g];    // folded z-gate bias
  const float bn  = b_ih[128 + g];
  const int nst = steps[b];

  float hself = embeds[b * HD + g];
  hl[g] = (_Float16)hself;

  unsigned short* xrow = Xb + (size_t)b * LMAXT * HD + g;

  // depth-4 ring prefetch of this thread's 3 W_ih elements
  float pr[4], pz[4], pn[4];
#pragma unroll
  for (int d = 0; d < 4; ++d) {
    const float* rw = W_ih + (size_t)seqL[d] * 192;
    pr[d] = rw[g]; pz[d] = rw[64 + g]; pn[d] = rw[128 + g];
  }

  union HU { h8 v; __half2 h[4]; };

  const int ngroups = (nst + 3) >> 2;
  for (int tg = 0; tg < ngroups; ++tg) {
    const int t = tg * 4;
#pragma unroll
    for (int u = 0; u < 4; ++u) {
      // ---- one GRU step (inline; no lambda so W stays SROA/registers) ----
      wave_lds_fence();                       // prev h write -> visible
      const h8* hp = (const h8*)hl;
      __half2 ar0{}, ar1{}, az0{}, az1{}, an0{}, an1{};
#pragma unroll
      for (int i = 0; i < 8; ++i) {
        HU hu; hu.v = hp[i];
#pragma unroll
        for (int j = 0; j < 4; ++j) {
          const __half2 ph = hu.h[j];
          const int k = i * 4 + j;
          if (j & 1) {
            ar1 = __hfma2(ph, wr2[k], ar1);
            az1 = __hfma2(ph, wz2[k], az1);
            an1 = __hfma2(ph, wn2[k], an1);
          } else {
            ar0 = __hfma2(ph, wr2[k], ar0);
            az0 = __hfma2(ph, wz2[k], az0);
            an0 = __hfma2(ph, wn2[k], an0);
          }
        }
      }
      const float sr = (__low2float(ar0) + __high2float(ar0)) +
                       (__low2float(ar1) + __high2float(ar1));
      const float sz = (__low2float(az0) + __high2float(az0)) +
                       (__low2float(az1) + __high2float(az1));
      const float sn = (__low2float(an0) + __high2float(an0)) +
                       (__low2float(an1) + __high2float(an1));
      const float ar = sr + br + pr[u];
      const float az = sz + bz + pz[u];
      const float ghn = sn + bhn;
      // sigmoid/tanh via exp2+rcp: rcp(inf)=0 handles saturation exactly
      const float rr = frcp(1.f + ex2(ar * -LOG2E));
      const float zz = frcp(1.f + ex2(az * -LOG2E));
      const float nx = (pn[u] + bn) + rr * ghn;
      const float th = 1.f - 2.f * frcp(1.f + ex2(nx * (2.f * LOG2E)));
      const float hn = th + zz * (hself - th);
      hself = hn;
      hl[g] = (_Float16)hn;
      if (t + u < nst) xrow[(size_t)(t + u) * HD] = f2bf(hn);
      // refill ring slot u for step t+u+4
      {
        int nt = t + u + 4;
        nt = (nt <= LMAXT + 1) ? nt : (LMAXT + 1);
        const float* rw = W_ih + (size_t)seqL[nt] * 192;
        pr[u] = rw[g]; pz[u] = rw[64 + g]; pn[u] = rw[128 + g];
      }
    }
  }
  // zero-fill padded rows (ws is re-poisoned before every call)
  for (int i = nst * HD + g; i < LMAXT * HD; i += 64)
    Xb[(size_t)b * (LMAXT * HD) + i] = 0;
}

// ---------------------------------------------------------------------------
// Kernel C: MFMA bf16 fused projection + logsumexp + NLL.
// Block = 512 threads = 8 waves sharing one (b, 32-row chunk); waves split
// the 257 column tiles (33 each -> 66 KB Wb stream per wave). Partial exp
// sums merge via LDS. Grid 640 blocks -> 20 waves/CU.
// ---------------------------------------------------------------------------
__global__ __launch_bounds__(512) void k_proj(
    const unsigned short* __restrict__ Xb,
    const unsigned short* __restrict__ Wb,
    const float* __restrict__ bo2,
    const int* __restrict__ seq, const int* __restrict__ steps,
    const float* __restrict__ b_out,
    float* __restrict__ loss_accum) {
  const int l  = threadIdx.x & 63;
  const int wv = threadIdx.x >> 6;         // 0..7 column-split wave id
  const int b  = blockIdx.x / 10;
  const int t0 = (blockIdx.x % 10) * 32;
  const int nst = steps[b];
  const bool active = (t0 < nst);          // block-uniform

  __shared__ float spart[CSPLIT][32];

  if (active) {
    const int lm = l & 15;
    const int q  = l >> 4;

    const unsigned short* xp0 = Xb + ((size_t)b * LMAXT + t0 + lm) * HD + q * 8;
    const bf16x8 a00 = ldb8(xp0);
    const bf16x8 a01 = ldb8(xp0 + 32);
    const bf16x8 a10 = ldb8(xp0 + 16 * HD);
    const bf16x8 a11 = ldb8(xp0 + 16 * HD + 32);

    float s[8];
#pragma unroll
    for (int i = 0; i < 8; ++i) s[i] = 0.f;

    const int ct0 = wv * 33;
    const int ct1 = (ct0 + 33 < NTILE) ? (ct0 + 33) : NTILE;   // wave 7: 26

    const unsigned short* wp = Wb + lm * 64 + q * 8;
    const float* bop = bo2 + lm;

    bf16x8 b0 = ldb8(wp + (size_t)ct0 * 1024);
    bf16x8 b1 = ldb8(wp + (size_t)ct0 * 1024 + 32);
    float  bo = bop[ct0 * 16];
    for (int ct = ct0; ct < ct1; ++ct) {
      bf16x8 nb0, nb1; float nbo;
      if (ct + 1 < ct1) {
        const unsigned short* wpn = wp + (size_t)(ct + 1) * 1024;
        nb0 = ldb8(wpn); nb1 = ldb8(wpn + 32); nbo = bop[(ct + 1) * 16];
      }
      f32x4 acc0 = {0.f, 0.f, 0.f, 0.f};
      f32x4 acc1 = {0.f, 0.f, 0.f, 0.f};
      acc0 = __builtin_amdgcn_mfma_f32_16x16x32_bf16(a00, b0, acc0, 0, 0, 0);
      acc0 = __builtin_amdgcn_mfma_f32_16x16x32_bf16(a01, b1, acc0, 0, 0, 0);
      acc1 = __builtin_amdgcn_mfma_f32_16x16x32_bf16(a10, b0, acc1, 0, 0, 0);
      acc1 = __builtin_amdgcn_mfma_f32_16x16x32_bf16(a11, b1, acc1, 0, 0, 0);
#pragma unroll
      for (int i = 0; i < 4; ++i) {
        s[i]     += ex2(fmaf(acc0[i], LOG2E, bo));
        s[4 + i] += ex2(fmaf(acc1[i], LOG2E, bo));
      }
      if (ct + 1 < ct1) { b0 = nb0; b1 = nb1; bo = nbo; }
    }

    // reduce across the 16 lanes (lm) sharing each row
#pragma unroll
    for (int m = 1; m < 16; m <<= 1) {
#pragma unroll
      for (int i = 0; i < 8; ++i) s[i] += __shfl_xor(s[i], m, 64);
    }
    // D-layout: lane q*16 holds rows q*4+i (tile0) / 16+q*4+i (tile1)
    if (lm == 0) {
#pragma unroll
      for (int i = 0; i < 4; ++i) {
        spart[wv][q * 4 + i]      = s[i];
        spart[wv][16 + q * 4 + i] = s[4 + i];
      }
    }
  }
  __syncthreads();

  float nll = 0.f;
  if (active && threadIdx.x < 32) {
    const int t = t0 + threadIdx.x;
    if (t < nst) {
      float ssum = 0.f;
#pragma unroll
      for (int c = 0; c < CSPLIT; ++c) ssum += spart[c][threadIdx.x];
      const int col = seq[b * SEQ_STRIDE + t + 1];
      // target logit from the SAME bf16 operands (consistent cancellation)
      const unsigned short* xr = Xb + ((size_t)b * LMAXT + t) * HD;
      const unsigned short* wc = Wb + (size_t)(col >> 4) * 1024 + (col & 15) * 64;
      float tl = b_out[col];
#pragma unroll 16
      for (int k = 0; k < 64; ++k)
        tl = fmaf(bf2f(xr[k]), bf2f(wc[k]), tl);
      nll = (30.f + __logf(ssum)) - tl;
    }
  }
  if (threadIdx.x < 64) {
#pragma unroll
    for (int off = 32; off; off >>= 1) nll += __shfl_down(nll, off, 64);
    if (threadIdx.x == 0) atomicAdd(loss_accum, nll);
  }
}

// ---------------------------------------------------------------------------
// Kernel D: finalize (loss_sum / count).
// ---------------------------------------------------------------------------
__global__ void k_final(const float* __restrict__ loss_accum,
                        const int* __restrict__ steps,
                        float* __restrict__ out) {
  if (threadIdx.x == 0 && blockIdx.x == 0) {
    int cnt = 0;
    for (int i = 0; i < NB; ++i) cnt += steps[i];
    out[0] = loss_accum[0] / (float)cnt;
  }
}

// ---------------------------------------------------------------------------
extern "C" void kernel_launch(void* const* d_in, const int* in_sizes, int n_in,
                              void* d_out, int out_size, void* d_ws,
                              size_t ws_size, hipStream_t stream) {
  const float* embeds  = (const float*)d_in[0];
  const float* true_fp = (const float*)d_in[1];
  const int*   perm    = (const int*)d_in[5];
  const float* W_ih    = (const float*)d_in[6];
  const float* b_ih    = (const float*)d_in[7];
  const float* W_hh    = (const float*)d_in[8];
  const float* b_hh    = (const float*)d_in[9];
  const float* W_out   = (const float*)d_in[10];
  const float* b_out   = (const float*)d_in[11];

  char*  ws     = (char*)d_ws;
  int*   seq    = (int*)(ws + SEQ_OFF);
  int*   steps  = (int*)(ws + STEPS_OFF);
  float* loss   = (float*)(ws + LOSS_OFF);
  unsigned short* Xb = (unsigned short*)(ws + XB_OFF);
  unsigned short* Wb = (unsigned short*)(ws + WB_OFF);
  float* bo2    = (float*)(ws + BO_OFF);
  float* out    = (float*)d_out;

  k_setup<<<NB, 64, 0, stream>>>(true_fp, perm, seq, steps, loss);
  k_prep<<<NTILE, 256, 0, stream>>>(W_out, b_out, Wb, bo2);
  k_gru<<<NB, 64, 0, stream>>>(embeds, W_ih, b_ih, W_hh, b_hh, seq, steps, Xb);
  k_proj<<<640, 512, 0, stream>>>(Xb, Wb, bo2, seq, steps, b_out, loss);
  k_final<<<1, 64, 0, stream>>>(loss, steps, out);
}

// Round 7
// 258.534 us; speedup vs baseline: 3.0095x; 1.0120x over previous
//
#include <hip/hip_runtime.h>
#include <hip/hip_fp16.h>
#include <cstdint>
#include <cstddef>

// Problem constants (fixed by reference)
#define NB      64      // batch
#define NBITS   4096
#define HD      64      // hidden
#define IN_DIM  4098
#define LMAXT   320
#define SEQ_STRIDE 336  // padded seq row (>= LMAX+2, mult of 16)
#define NTILE   257     // col tiles of 16 (4112 padded cols)
#define LOG2E   1.44269504088896340f
#define CSPLIT  8       // column-split waves per k_proj block

// Workspace layout (bytes), all 256-aligned
static constexpr size_t SEQ_OFF   = 0;                               // 86016
static constexpr size_t STEPS_OFF = 86016;                           // 256
static constexpr size_t LOSS_OFF  = 86272;                           // 256
static constexpr size_t XB_OFF    = 86528;                           // 64*320*64*2 = 2621440
static constexpr size_t WB_OFF    = XB_OFF + 2621440;                // 257*1024*2 = 526336
static constexpr size_t BO_OFF    = WB_OFF + 526336;                 // 4112*4

typedef __bf16    bf16x8 __attribute__((ext_vector_type(8)));
typedef float     f32x4  __attribute__((ext_vector_type(4)));
typedef _Float16  h2     __attribute__((ext_vector_type(2)));

// glibc's math.h macro-expands a declaration named __exp2f -> do NOT use that
// identifier; go straight to the HW builtin (v_exp_f32).
__device__ __forceinline__ float ex2(float x) {
#if __has_builtin(__builtin_amdgcn_exp2f)
  return __builtin_amdgcn_exp2f(x);
#else
  return __expf(x * 0.6931471805599453f);
#endif
}
// raw v_rcp_f32 (~1 ulp): keeps the gate chain off the slow exact-div sequence
__device__ __forceinline__ float frcp(float x) {
#if __has_builtin(__builtin_amdgcn_rcpf)
  return __builtin_amdgcn_rcpf(x);
#else
  return 1.f / x;
#endif
}

__device__ __forceinline__ unsigned short f2bf(float f) {
  unsigned u = __float_as_uint(f);
  unsigned r = u + 0x7FFFu + ((u >> 16) & 1u);   // RNE
  return (unsigned short)(r >> 16);
}
__device__ __forceinline__ float bf2f(unsigned short u) {
  return __uint_as_float((unsigned)u << 16);
}
__device__ __forceinline__ bf16x8 ldb8(const unsigned short* p) {
  return *(const bf16x8*)p;
}
__device__ __forceinline__ void wave_lds_fence() {
  __asm__ __volatile__("s_waitcnt lgkmcnt(0)" ::: "memory");
}

// ---------------------------------------------------------------------------
// Kernel A: compaction. Stage 1 builds a 4096-bit LDS mask from a coalesced
// row read; stage 2 scans in perm order against LDS (no HBM gather).
// ---------------------------------------------------------------------------
__global__ __launch_bounds__(64) void k_setup(
    const float* __restrict__ true_fp, const int* __restrict__ perm,
    int* __restrict__ seq, int* __restrict__ steps,
    float* __restrict__ loss_accum) {
  const int b = blockIdx.x;
  const int j = threadIdx.x;
  if (b == 0 && j == 0) *loss_accum = 0.f;
  __shared__ unsigned long long bits[64];
  const float* row = true_fp + (size_t)b * NBITS;

  {
    const float4* rv = (const float4*)(row + j * 64);
    unsigned long long w = 0ull;
#pragma unroll
    for (int i = 0; i < 16; ++i) {
      const float4 v = rv[i];
      w |= (unsigned long long)(v.x > 0.f) << (4 * i + 0);
      w |= (unsigned long long)(v.y > 0.f) << (4 * i + 1);
      w |= (unsigned long long)(v.z > 0.f) << (4 * i + 2);
      w |= (unsigned long long)(v.w > 0.f) << (4 * i + 3);
    }
    bits[j] = w;
  }
  wave_lds_fence();

  int* srow = seq + b * SEQ_STRIDE;
  int base = 0;
  for (int c0 = 0; c0 < IN_DIM; c0 += 64) {
    const int col = c0 + j;
    bool pred = false;
    if (col < IN_DIM) {
      if (col == 0 || col == IN_DIM - 1) pred = true;
      else {
        const int p = perm[col - 1];
        pred = (bits[p >> 6] >> (p & 63)) & 1ull;
      }
    }
    const unsigned long long mask = __ballot(pred);
    const int prefix = __popcll(mask & ((1ull << j) - 1ull));
    const int idx = base + prefix;
    if (pred && idx <= LMAXT) srow[idx] = col;
    base += __popcll(mask);
  }
  const int cap = (base <= LMAXT + 1) ? base : (LMAXT + 1);
  for (int i = cap + j; i < SEQ_STRIDE; i += 64) srow[i] = 0;
  if (j == 0) {
    int s = base - 1;
    if (s > LMAXT) s = LMAXT;
    steps[b] = s;
  }
}

// ---------------------------------------------------------------------------
// Kernel A2: bf16 fragment-major W tiles + pre-scaled shifted bias
// bo2[col] = (b_out[col]-30)*log2(e); pad -1e30. Coalesced W_out reads.
// ---------------------------------------------------------------------------
__global__ __launch_bounds__(256) void k_prep(
    const float* __restrict__ W_out, const float* __restrict__ b_out,
    unsigned short* __restrict__ Wb, float* __restrict__ bo2) {
  const int c = blockIdx.x;            // 0..256
  const int t = threadIdx.x;
  const int m = t & 15;                // col within tile
  const int col = c * 16 + m;
  const bool cok = col < IN_DIM;
#pragma unroll
  for (int kp = 0; kp < 4; ++kp) {
    const int k = kp * 16 + (t >> 4);
    const float v = cok ? W_out[(size_t)k * IN_DIM + col] : 0.f;
    Wb[c * 1024 + m * 64 + k] = f2bf(v);
  }
  if (t < 16) {
    const int cc = c * 16 + t;
    bo2[c * 16 + t] = (cc < IN_DIM) ? (b_out[cc] - 30.f) * LOG2E : -1e30f;
  }
}

// ---------------------------------------------------------------------------
// Kernel B: GRU recurrence. ONE WAVE per batch row, zero barriers.
// R6 post-mortem: __half2 w[32] arrays were NOT register-allocated
// (VGPR_Count stayed 84 -> ~96 spill-reads/step -> 1008 cyc/step). Fix:
// 96 individually-NAMED h2 ext-vector variables (pure SSA, SROA-proof) +
// amdgpu_waves_per_eu(1,1) for the full 512-VGPR budget. Dots are plain
// acc += h*w on 2-wide f16 vectors -> v_pk_fma_f16. Depth-2 named-variable
// W_ih prefetch. Gates via exp2+rcp.
// ---------------------------------------------------------------------------
#define W_DEF(i) h2 wr##i, wz##i, wn##i;
#define W_INIT(i) {                                                  \
    const float* w0_ = W_hh + (size_t)(2 * (i)) * 192;               \
    const float* w1_ = W_hh + (size_t)(2 * (i) + 1) * 192;           \
    wr##i[0] = (_Float16)w0_[g];       wr##i[1] = (_Float16)w1_[g];  \
    wz##i[0] = (_Float16)w0_[64 + g];  wz##i[1] = (_Float16)w1_[64 + g]; \
    wn##i[0] = (_Float16)w0_[128 + g]; wn##i[1] = (_Float16)w1_[128 + g]; }
#define W_FMA(i, s) { const h2 hp_ = hp2[i];                         \
    ar##s += hp_ * wr##i;                                            \
    az##s += hp_ * wz##i;                                            \
    an##s += hp_ * wn##i; }

__global__ __launch_bounds__(64)
__attribute__((amdgpu_waves_per_eu(1, 1)))
void k_gru(
    const float* __restrict__ embeds,
    const float* __restrict__ W_ih, const float* __restrict__ b_ih,
    const float* __restrict__ W_hh, const float* __restrict__ b_hh,
    const int* __restrict__ seq, const int* __restrict__ steps,
    unsigned short* __restrict__ Xb) {
  const int b = blockIdx.x;
  const int g = threadIdx.x;   // 0..63

  __shared__ __align__(16) _Float16 hl[HD];
  __shared__ int seqL[LMAXT + 2];

  for (int i = g; i < LMAXT + 2; i += 64) seqL[i] = seq[b * SEQ_STRIDE + i];

  // 96 named h2 registers: W_hh columns for unit g over k-pairs
  W_DEF(0)  W_DEF(1)  W_DEF(2)  W_DEF(3)  W_DEF(4)  W_DEF(5)  W_DEF(6)  W_DEF(7)
  W_DEF(8)  W_DEF(9)  W_DEF(10) W_DEF(11) W_DEF(12) W_DEF(13) W_DEF(14) W_DEF(15)
  W_DEF(16) W_DEF(17) W_DEF(18) W_DEF(19) W_DEF(20) W_DEF(21) W_DEF(22) W_DEF(23)
  W_DEF(24) W_DEF(25) W_DEF(26) W_DEF(27) W_DEF(28) W_DEF(29) W_DEF(30) W_DEF(31)
  W_INIT(0)  W_INIT(1)  W_INIT(2)  W_INIT(3)  W_INIT(4)  W_INIT(5)  W_INIT(6)  W_INIT(7)
  W_INIT(8)  W_INIT(9)  W_INIT(10) W_INIT(11) W_INIT(12) W_INIT(13) W_INIT(14) W_INIT(15)
  W_INIT(16) W_INIT(17) W_INIT(18) W_INIT(19) W_INIT(20) W_INIT(21) W_INIT(22) W_INIT(23)
  W_INIT(24) W_INIT(25) W_INIT(26) W_INIT(27) W_INIT(28) W_INIT(29) W_INIT(30) W_INIT(31)

  const float bhn = b_hh[128 + g];
  const float br  = b_ih[g] + b_hh[g];              // folded r-gate bias
  const float bz  = b_ih[64 + g] + b_hh[64 + g];    // folded z-gate bias
  const float bn  = b_ih[128 + g];
  const int nst = steps[b];

  float hself = embeds[b * HD + g];
  hl[g] = (_Float16)hself;

  unsigned short* xrow = Xb + (size_t)b * LMAXT * HD + g;

  // depth-2 named-variable prefetch of this thread's 3 W_ih elements
  float c_r, c_z, c_n, n_r, n_z, n_n;
  {
    const float* rw0 = W_ih + (size_t)seqL[0] * 192;
    c_r = rw0[g]; c_z = rw0[64 + g]; c_n = rw0[128 + g];
    const float* rw1 = W_ih + (size_t)seqL[1] * 192;
    n_r = rw1[g]; n_z = rw1[64 + g]; n_n = rw1[128 + g];
  }

  h2 hz; hz[0] = (_Float16)0.f; hz[1] = (_Float16)0.f;

  for (int t = 0; t < nst; ++t) {
    // issue prefetch for step t+2 (in flight across ~2 full steps)
    int nt = t + 2; nt = (nt <= LMAXT + 1) ? nt : (LMAXT + 1);
    const float* rw = W_ih + (size_t)seqL[nt] * 192;
    const float t_r = rw[g], t_z = rw[64 + g], t_n = rw[128 + g];

    wave_lds_fence();                       // prev h writes visible
    const h2* hp2 = (const h2*)hl;
    h2 ar0 = hz, ar1 = hz, az0 = hz, az1 = hz, an0 = hz, an1 = hz;
    W_FMA(0, 0)  W_FMA(1, 1)  W_FMA(2, 0)  W_FMA(3, 1)
    W_FMA(4, 0)  W_FMA(5, 1)  W_FMA(6, 0)  W_FMA(7, 1)
    W_FMA(8, 0)  W_FMA(9, 1)  W_FMA(10, 0) W_FMA(11, 1)
    W_FMA(12, 0) W_FMA(13, 1) W_FMA(14, 0) W_FMA(15, 1)
    W_FMA(16, 0) W_FMA(17, 1) W_FMA(18, 0) W_FMA(19, 1)
    W_FMA(20, 0) W_FMA(21, 1) W_FMA(22, 0) W_FMA(23, 1)
    W_FMA(24, 0) W_FMA(25, 1) W_FMA(26, 0) W_FMA(27, 1)
    W_FMA(28, 0) W_FMA(29, 1) W_FMA(30, 0) W_FMA(31, 1)

    const float sr = ((float)ar0[0] + (float)ar0[1]) +
                     ((float)ar1[0] + (float)ar1[1]);
    const float sz = ((float)az0[0] + (float)az0[1]) +
                     ((float)az1[0] + (float)az1[1]);
    const float sn = ((float)an0[0] + (float)an0[1]) +
                     ((float)an1[0] + (float)an1[1]);
    const float ar = sr + br + c_r;
    const float az = sz + bz + c_z;
    const float ghn = sn + bhn;
    // sigmoid/tanh via exp2+rcp: rcp(inf)=0 handles saturation exactly
    const float rr = frcp(1.f + ex2(ar * -LOG2E));
    const float zz = frcp(1.f + ex2(az * -LOG2E));
    const float nx = (c_n + bn) + rr * ghn;
    const float th = 1.f - 2.f * frcp(1.f + ex2(nx * (2.f * LOG2E)));
    const float hn = th + zz * (hself - th);
    hself = hn;
    hl[g] = (_Float16)hn;
    xrow[(size_t)t * HD] = f2bf(hn);

    c_r = n_r; c_z = n_z; c_n = n_n;
    n_r = t_r; n_z = t_z; n_n = t_n;
  }
  // zero-fill padded rows (ws is re-poisoned before every call)
  for (int i = nst * HD + g; i < LMAXT * HD; i += 64)
    Xb[(size_t)b * (LMAXT * HD) + i] = 0;
}

// ---------------------------------------------------------------------------
// Kernel C: MFMA bf16 fused projection + logsumexp + NLL.
// Block = 512 threads = 8 waves sharing one (b, 32-row chunk); waves split
// the 257 column tiles (33 each -> 66 KB Wb stream per wave). Partial exp
// sums merge via LDS. Grid 640 blocks -> 20 waves/CU.
// ---------------------------------------------------------------------------
__global__ __launch_bounds__(512) void k_proj(
    const unsigned short* __restrict__ Xb,
    const unsigned short* __restrict__ Wb,
    const float* __restrict__ bo2,
    const int* __restrict__ seq, const int* __restrict__ steps,
    const float* __restrict__ b_out,
    float* __restrict__ loss_accum) {
  const int l  = threadIdx.x & 63;
  const int wv = threadIdx.x >> 6;         // 0..7 column-split wave id
  const int b  = blockIdx.x / 10;
  const int t0 = (blockIdx.x % 10) * 32;
  const int nst = steps[b];
  const bool active = (t0 < nst);          // block-uniform

  __shared__ float spart[CSPLIT][32];

  if (active) {
    const int lm = l & 15;
    const int q  = l >> 4;

    const unsigned short* xp0 = Xb + ((size_t)b * LMAXT + t0 + lm) * HD + q * 8;
    const bf16x8 a00 = ldb8(xp0);
    const bf16x8 a01 = ldb8(xp0 + 32);
    const bf16x8 a10 = ldb8(xp0 + 16 * HD);
    const bf16x8 a11 = ldb8(xp0 + 16 * HD + 32);

    float s[8];
#pragma unroll
    for (int i = 0; i < 8; ++i) s[i] = 0.f;

    const int ct0 = wv * 33;
    const int ct1 = (ct0 + 33 < NTILE) ? (ct0 + 33) : NTILE;   // wave 7: 26

    const unsigned short* wp = Wb + lm * 64 + q * 8;
    const float* bop = bo2 + lm;

    bf16x8 b0 = ldb8(wp + (size_t)ct0 * 1024);
    bf16x8 b1 = ldb8(wp + (size_t)ct0 * 1024 + 32);
    float  bo = bop[ct0 * 16];
    for (int ct = ct0; ct < ct1; ++ct) {
      bf16x8 nb0, nb1; float nbo;
      if (ct + 1 < ct1) {
        const unsigned short* wpn = wp + (size_t)(ct + 1) * 1024;
        nb0 = ldb8(wpn); nb1 = ldb8(wpn + 32); nbo = bop[(ct + 1) * 16];
      }
      f32x4 acc0 = {0.f, 0.f, 0.f, 0.f};
      f32x4 acc1 = {0.f, 0.f, 0.f, 0.f};
      acc0 = __builtin_amdgcn_mfma_f32_16x16x32_bf16(a00, b0, acc0, 0, 0, 0);
      acc0 = __builtin_amdgcn_mfma_f32_16x16x32_bf16(a01, b1, acc0, 0, 0, 0);
      acc1 = __builtin_amdgcn_mfma_f32_16x16x32_bf16(a10, b0, acc1, 0, 0, 0);
      acc1 = __builtin_amdgcn_mfma_f32_16x16x32_bf16(a11, b1, acc1, 0, 0, 0);
#pragma unroll
      for (int i = 0; i < 4; ++i) {
        s[i]     += ex2(fmaf(acc0[i], LOG2E, bo));
        s[4 + i] += ex2(fmaf(acc1[i], LOG2E, bo));
      }
      if (ct + 1 < ct1) { b0 = nb0; b1 = nb1; bo = nbo; }
    }

    // reduce across the 16 lanes (lm) sharing each row
#pragma unroll
    for (int m = 1; m < 16; m <<= 1) {
#pragma unroll
      for (int i = 0; i < 8; ++i) s[i] += __shfl_xor(s[i], m, 64);
    }
    // D-layout: lane q*16 holds rows q*4+i (tile0) / 16+q*4+i (tile1)
    if (lm == 0) {
#pragma unroll
      for (int i = 0; i < 4; ++i) {
        spart[wv][q * 4 + i]      = s[i];
        spart[wv][16 + q * 4 + i] = s[4 + i];
      }
    }
  }
  __syncthreads();

  float nll = 0.f;
  if (active && threadIdx.x < 32) {
    const int t = t0 + threadIdx.x;
    if (t < nst) {
      float ssum = 0.f;
#pragma unroll
      for (int c = 0; c < CSPLIT; ++c) ssum += spart[c][threadIdx.x];
      const int col = seq[b * SEQ_STRIDE + t + 1];
      // target logit from the SAME bf16 operands (consistent cancellation)
      const unsigned short* xr = Xb + ((size_t)b * LMAXT + t) * HD;
      const unsigned short* wc = Wb + (size_t)(col >> 4) * 1024 + (col & 15) * 64;
      float tl = b_out[col];
#pragma unroll 16
      for (int k = 0; k < 64; ++k)
        tl = fmaf(bf2f(xr[k]), bf2f(wc[k]), tl);
      nll = (30.f + __logf(ssum)) - tl;
    }
  }
  if (threadIdx.x < 64) {
#pragma unroll
    for (int off = 32; off; off >>= 1) nll += __shfl_down(nll, off, 64);
    if (threadIdx.x == 0) atomicAdd(loss_accum, nll);
  }
}

// ---------------------------------------------------------------------------
// Kernel D: finalize (loss_sum / count).
// ---------------------------------------------------------------------------
__global__ void k_final(const float* __restrict__ loss_accum,
                        const int* __restrict__ steps,
                        float* __restrict__ out) {
  if (threadIdx.x == 0 && blockIdx.x == 0) {
    int cnt = 0;
    for (int i = 0; i < NB; ++i) cnt += steps[i];
    out[0] = loss_accum[0] / (float)cnt;
  }
}

// ---------------------------------------------------------------------------
extern "C" void kernel_launch(void* const* d_in, const int* in_sizes, int n_in,
                              void* d_out, int out_size, void* d_ws,
                              size_t ws_size, hipStream_t stream) {
  const float* embeds  = (const float*)d_in[0];
  const float* true_fp = (const float*)d_in[1];
  const int*   perm    = (const int*)d_in[5];
  const float* W_ih    = (const float*)d_in[6];
  const float* b_ih    = (const float*)d_in[7];
  const float* W_hh    = (const float*)d_in[8];
  const float* b_hh    = (const float*)d_in[9];
  const float* W_out   = (const float*)d_in[10];
  const float* b_out   = (const float*)d_in[11];

  char*  ws     = (char*)d_ws;
  int*   seq    = (int*)(ws + SEQ_OFF);
  int*   steps  = (int*)(ws + STEPS_OFF);
  float* loss   = (float*)(ws + LOSS_OFF);
  unsigned short* Xb = (unsigned short*)(ws + XB_OFF);
  unsigned short* Wb = (unsigned short*)(ws + WB_OFF);
  float* bo2    = (float*)(ws + BO_OFF);
  float* out    = (float*)d_out;

  k_setup<<<NB, 64, 0, stream>>>(true_fp, perm, seq, steps, loss);
  k_prep<<<NTILE, 256, 0, stream>>>(W_out, b_out, Wb, bo2);
  k_gru<<<NB, 64, 0, stream>>>(embeds, W_ih, b_ih, W_hh, b_hh, seq, steps, Xb);
  k_proj<<<640, 512, 0, stream>>>(Xb, Wb, bo2, seq, steps, b_out, loss);
  k_final<<<1, 64, 0, stream>>>(loss, steps, out);
}